// Round 3
// baseline (105.382 us; speedup 1.0000x reference)
//
#include <hip/hip_runtime.h>

// TanhAttention: B=4, L=512, D=256
//   scores[b,i,j] = sum_d tanh(H[b,i,d]+H[b,j,d]) * w[d] + bias
//   alpha = softmax_j(scores); r = alpha @ H
// Outputs concatenated: r (524288 floats) then alpha (1048576 floats).
//
// Math: tanh(x) = 1 - 2/(1+e^{2x}); with E = exp2(K*h), K = 2*log2(e):
//   e^{2(hi+hj)} = Ei*Ej  ->  score_shifted = -2*sum_d w_d * rcp(fma(Ei,Ej,1))
// (softmax shift cancels sum(w)+bias -> bias unused; symmetric -> upper tiles only).
//
// R13: 8-wave straight-line score kernel (best known: 87.6us).
// R14: phase-2 widened to 8 waves -> Δ=0 (phase 2 L2-BW-bound or not the lever).
// R15: score w->SGPR + launch pin -> +1.9us REGRESSION (readfirstlane overhead;
//      occupancy was already LDS-bound at 3 blocks/CU). Reverted here.
// R16: ATTRIBUTION ROUND. score_kernel is idempotent (pure function, no RMW):
//      launch it TWICE; dur_us delta vs 87.6 baseline == exact T_score through
//      the only trusted channel. Decides next structural target: score (~28?)
//      vs softmax_r+dispatch overhead. Bench number will regress by design.

#define B_ 4
#define L_ 512
#define D_ 256
#define NT16 32         // L_/16
#define NTRI16 528      // 32*33/2 upper-tri 16x16 tiles per batch
#define ST 36           // staging slot stride (dwords): conflict-free, 16B-aligned

typedef float v4f __attribute__((ext_vector_type(4)));

__global__ __launch_bounds__(512) void score_kernel(
    const float* __restrict__ H, const float* __restrict__ w,
    float* __restrict__ sOut)
{
    __shared__ __align__(16) float lds[8][32 * ST];   // 36.9 KB staging (E values)
    __shared__ float pr[8][16][17];                   // 8.7 KB partial scores
    __shared__ float sc[16][17];                      // 1.1 KB mirror transpose

    const int tid  = threadIdx.x;
    const int wv   = tid >> 6;               // D-slice index 0..7
    const int lane = tid & 63;
    const int blk  = blockIdx.x;             // 0 .. 2111 (one block per (b,tile))
    const int b    = blk / NTRI16;
    const int t    = blk - b * NTRI16;
    // closed-form upper-tri index: n = 32-ti solves n(n+1)/2 >= u, u = 528-t
    const int u  = NTRI16 - t;
    int n = (int)((__builtin_amdgcn_sqrtf((float)(8 * u + 1)) - 1.0f) * 0.5f);
    while (n * (n + 1) / 2 < u) ++n;         // fp fixup, <=2 iters
    const int ti = NT16 - n;
    const int tj = ti + (t - (NTRI16 - n * (n + 1) / 2));
    const int i0 = ti * 16, j0 = tj * 16;
    const int dq0 = wv * 32;                 // this wave's 32-d slice
    const float K = 2.8853900817779268f;     // 2*log2(e)
    const float* Hb = H + (size_t)b * L_ * D_;

    const int ig = lane >> 3, jg = lane & 7; // i = i0+ig+8*ii, j = j0+jg+8*jj

    float* const buf = &lds[wv][0];

    // ---- stage this wave's 32 rows x 32 d: 256 quads / 64 lanes = 4 each ----
    float4 hv[4];
    int slot[4], scol[4];
    #pragma unroll
    for (int s = 0; s < 4; ++s) {
        int idx = lane + 64 * s;
        int r = idx >> 3, q = idx & 7;
        int srow = (r < 16) ? (i0 + r) : (j0 + r - 16);
        slot[s] = r;
        scol[s] = 4 * q;
        hv[s] = *(const float4*)(Hb + srow * D_ + dq0 + 4 * q);   // batched loads
    }
    #pragma unroll
    for (int s = 0; s < 4; ++s) {
        v4f ev;
        ev.x = __builtin_amdgcn_exp2f(hv[s].x * K);
        ev.y = __builtin_amdgcn_exp2f(hv[s].y * K);
        ev.z = __builtin_amdgcn_exp2f(hv[s].z * K);
        ev.w = __builtin_amdgcn_exp2f(hv[s].w * K);
        *(v4f*)&buf[slot[s] * ST + scol[s]] = ev;
    }

    // batch the 8 uniform w-quads (one SMEM latency)
    float4 wqa[8];
    #pragma unroll
    for (int q = 0; q < 8; ++q)
        wqa[q] = *(const float4*)(w + dq0 + 4 * q);

    __builtin_amdgcn_wave_barrier();         // pin ds_writes before reads (own wave only)

    v4f acc[2][2];
    #pragma unroll
    for (int ii = 0; ii < 2; ++ii)
        #pragma unroll
        for (int jj = 0; jj < 2; ++jj) acc[ii][jj] = (v4f){0.f, 0.f, 0.f, 0.f};

    #pragma unroll
    for (int q = 0; q < 8; ++q) {            // 4-d block per step
        v4f wvv; wvv.x = wqa[q].x; wvv.y = wqa[q].y; wvv.z = wqa[q].z; wvv.w = wqa[q].w;
        v4f Ei[2], Ej[2];
        #pragma unroll
        for (int ii = 0; ii < 2; ++ii)       // slots ii*8+ig: all 32 banks once
            Ei[ii] = *(const v4f*)&buf[(ii * 8 + ig) * ST + 4 * q];
        #pragma unroll
        for (int jj = 0; jj < 2; ++jj)
            Ej[jj] = *(const v4f*)&buf[(16 + jj * 8 + jg) * ST + 4 * q];
        #pragma unroll
        for (int ii = 0; ii < 2; ++ii)
            #pragma unroll
            for (int jj = 0; jj < 2; ++jj) {
                v4f den = Ei[ii] * Ej[jj] + 1.0f;
                v4f rr;
                rr.x = __builtin_amdgcn_rcpf(den.x);
                rr.y = __builtin_amdgcn_rcpf(den.y);
                rr.z = __builtin_amdgcn_rcpf(den.z);
                rr.w = __builtin_amdgcn_rcpf(den.w);
                acc[ii][jj] += wvv * rr;
            }
    }

    // ---- partials to LDS ----
    #pragma unroll
    for (int ii = 0; ii < 2; ++ii)
        #pragma unroll
        for (int jj = 0; jj < 2; ++jj) {
            v4f a = acc[ii][jj];
            pr[wv][ig + 8 * ii][jg + 8 * jj] = a.x + a.y + a.z + a.w;
        }
    __syncthreads();

    // ---- combine 8 slices; threads 0..255 own one tile element each ----
    float val = 0.0f;
    const int row = (tid >> 4) & 15, col = tid & 15;
    if (tid < 256) {
        #pragma unroll
        for (int k = 0; k < 8; ++k) val += pr[k][row][col];
        val *= -2.0f;                        // shifted score
        sOut[((size_t)b * L_ + i0 + row) * L_ + j0 + col] = val;   // upper, coalesced
    }
    if (ti != tj) {                          // mirror via LDS transpose (block-uniform)
        if (tid < 256) sc[row][col] = val;
        __syncthreads();
        if (tid < 256)
            sOut[((size_t)b * L_ + j0 + row) * L_ + i0 + col] = sc[col][row];
    }
}

// Phase 2 (R14, neutral vs R7): 512 blocks x 512 thr (8 waves); 4 rows/block.
// Softmax on waves 0..3, r-phase wave w owns j in [64w,64w+64), LDS reduce.
__global__ __launch_bounds__(512) void softmax_r_kernel(
    const float* __restrict__ H, float* __restrict__ rOut, float* __restrict__ aOut)
{
    __shared__ float sc[4][L_];      // alpha rows, 8 KB
    __shared__ float pr[8][4][D_];   // per-wave partial r, 32 KB

    const int tid  = threadIdx.x;
    const int blk  = blockIdx.x;     // 0..511
    const int b    = blk >> 7;
    const int i0   = (blk & 127) * 4;
    const int wv   = tid >> 6;       // wave 0..7
    const int lane = tid & 63;
    const float* Hb = H + (size_t)b * L_ * D_;
    const float L2E = 1.4426950408889634f;

    // ---- softmax: wave wv (<4) handles row wv ----
    if (wv < 4) {
        const int row = wv;
        float* aRow = aOut + ((size_t)b * L_ + i0 + row) * L_;
        float v[8];
        float m = -1e30f;
        #pragma unroll
        for (int k = 0; k < 8; ++k) {
            v[k] = aRow[lane + 64 * k];      // coalesced score reads (L2-hot)
            m = fmaxf(m, v[k]);
        }
        #pragma unroll
        for (int off = 1; off < 64; off <<= 1)
            m = fmaxf(m, __shfl_xor(m, off, 64));
        float s = 0.0f;
        #pragma unroll
        for (int k = 0; k < 8; ++k) {
            v[k] = __builtin_amdgcn_exp2f((v[k] - m) * L2E);
            s += v[k];
        }
        #pragma unroll
        for (int off = 1; off < 64; off <<= 1)
            s += __shfl_xor(s, off, 64);
        const float inv = __builtin_amdgcn_rcpf(s);
        #pragma unroll
        for (int k = 0; k < 8; ++k) {
            float a = v[k] * inv;
            sc[row][lane + 64 * k] = a;
            aRow[lane + 64 * k] = a;         // overwrite scores with alpha in place
        }
    }
    __syncthreads();

    // ---- r-phase: wave-cooperative over j, 64 rows per wave ----
    const int jbase = 64 * wv;
    v4f racc[4];
    #pragma unroll
    for (int r = 0; r < 4; ++r) racc[r] = (v4f){0.f, 0.f, 0.f, 0.f};
    const v4f* Hb4 = (const v4f*)Hb;         // [512][64]

    #pragma unroll 4
    for (int js = 0; js < 64; js += 4) {
        v4f av[4];
        #pragma unroll
        for (int r = 0; r < 4; ++r)
            av[r] = *(const v4f*)&sc[r][jbase + js];   // b128 uniform broadcast
        #pragma unroll
        for (int q = 0; q < 4; ++q) {
            v4f h = Hb4[(size_t)(jbase + js + q) * (D_ / 4) + lane];
            #pragma unroll
            for (int r = 0; r < 4; ++r)
                racc[r] += av[r][q] * h;
        }
    }
    #pragma unroll
    for (int r = 0; r < 4; ++r)
        *(v4f*)&pr[wv][r][4 * lane] = racc[r];
    __syncthreads();

    // ---- reduce 8 wave-partials, write r (threads 0..255) ----
    if (tid < 256) {
        const int fq  = tid & 63;        // float4 index in D
        const int row = tid >> 6;        // 0..3
        v4f s = *(const v4f*)&pr[0][row][4 * fq];
        #pragma unroll
        for (int k = 1; k < 8; ++k)
            s += *(const v4f*)&pr[k][row][4 * fq];
        *(v4f*)&rOut[((size_t)b * L_ + i0 + row) * D_ + 4 * fq] = s;
    }
}

extern "C" void kernel_launch(void* const* d_in, const int* in_sizes, int n_in,
                              void* d_out, int out_size, void* d_ws, size_t ws_size,
                              hipStream_t stream) {
    const float* H = (const float*)d_in[0];
    const float* w = (const float*)d_in[1];
    // d_in[2] (bias) unused: softmax shift-invariance cancels it.
    float* rOut = (float*)d_out;
    float* aOut = rOut + (size_t)B_ * L_ * D_;   // alpha region doubles as score scratch

    // R16 attribution: score twice (idempotent, stream-serialized).
    // dur_us - 85.7 == T_score. Remove the duplicate next round.
    score_kernel<<<dim3(B_ * NTRI16), 512, 0, stream>>>(H, w, aOut);
    score_kernel<<<dim3(B_ * NTRI16), 512, 0, stream>>>(H, w, aOut);
    softmax_r_kernel<<<dim3(B_ * (L_ / 4)), 512, 0, stream>>>(H, rOut, aOut);
}

// Round 4
// 86.005 us; speedup vs baseline: 1.2253x; 1.2253x over previous
//
#include <hip/hip_runtime.h>

// TanhAttention: B=4, L=512, D=256
//   scores[b,i,j] = sum_d tanh(H[b,i,d]+H[b,j,d]) * w[d] + bias
//   alpha = softmax_j(scores); r = alpha @ H
// Outputs concatenated: r (524288 floats) then alpha (1048576 floats).
//
// Math: tanh(x) = 1 - 2/(1+e^{2x}); with E = exp2(K*h), K = 2*log2(e):
//   e^{2(hi+hj)} = Ei*Ej  ->  score_shifted = -2*sum_d w_d * rcp(fma(Ei,Ej,1))
// (softmax shift cancels sum(w)+bias -> bias unused; symmetric -> upper tiles only).
//
// R13: 8-wave straight-line score kernel (best known total: 87.6us).
// R14: phase-2 waves 4->8 -> Δ=0 (TLP-insensitive => BW-bound, consistent w/ L2 model).
// R15: score w->SGPR + pin -> +1.9us REGRESSION (reverted).
// R16: attribution: T_score = 17.8us (incl. 1 gap); F + T_softmax = 69.8us.
//      Score is near its VALU+trans issue floor (~12.5us) -> small slack there.
// R17: softmax_r L2-traffic cut. r-phase read H[b] per block: 512 blocks x 512KB
//      = 256MB L2 = 7.4us floor (dominates T2). Rows/block 4->8 (256 blocks):
//      128MB (3.7us), balanced vs VALU floor (3.4us). sc[8][512] (16KB, A/B)
//      UNIONed with pr[8][8][256] (64KB, C; sc dead) -> 64KB LDS, 2 blocks/CU.
//      Predict T2 8-10 -> ~5.5-6: dur 87.6 -> ~83-84.5.

#define B_ 4
#define L_ 512
#define D_ 256
#define NT16 32         // L_/16
#define NTRI16 528      // 32*33/2 upper-tri 16x16 tiles per batch
#define ST 36           // staging slot stride (dwords): conflict-free, 16B-aligned

typedef float v4f __attribute__((ext_vector_type(4)));

__global__ __launch_bounds__(512) void score_kernel(
    const float* __restrict__ H, const float* __restrict__ w,
    float* __restrict__ sOut)
{
    __shared__ __align__(16) float lds[8][32 * ST];   // 36.9 KB staging (E values)
    __shared__ float pr[8][16][17];                   // 8.7 KB partial scores
    __shared__ float sc[16][17];                      // 1.1 KB mirror transpose

    const int tid  = threadIdx.x;
    const int wv   = tid >> 6;               // D-slice index 0..7
    const int lane = tid & 63;
    const int blk  = blockIdx.x;             // 0 .. 2111 (one block per (b,tile))
    const int b    = blk / NTRI16;
    const int t    = blk - b * NTRI16;
    // closed-form upper-tri index: n = 32-ti solves n(n+1)/2 >= u, u = 528-t
    const int u  = NTRI16 - t;
    int n = (int)((__builtin_amdgcn_sqrtf((float)(8 * u + 1)) - 1.0f) * 0.5f);
    while (n * (n + 1) / 2 < u) ++n;         // fp fixup, <=2 iters
    const int ti = NT16 - n;
    const int tj = ti + (t - (NTRI16 - n * (n + 1) / 2));
    const int i0 = ti * 16, j0 = tj * 16;
    const int dq0 = wv * 32;                 // this wave's 32-d slice
    const float K = 2.8853900817779268f;     // 2*log2(e)
    const float* Hb = H + (size_t)b * L_ * D_;

    const int ig = lane >> 3, jg = lane & 7; // i = i0+ig+8*ii, j = j0+jg+8*jj

    float* const buf = &lds[wv][0];

    // ---- stage this wave's 32 rows x 32 d: 256 quads / 64 lanes = 4 each ----
    float4 hv[4];
    int slot[4], scol[4];
    #pragma unroll
    for (int s = 0; s < 4; ++s) {
        int idx = lane + 64 * s;
        int r = idx >> 3, q = idx & 7;
        int srow = (r < 16) ? (i0 + r) : (j0 + r - 16);
        slot[s] = r;
        scol[s] = 4 * q;
        hv[s] = *(const float4*)(Hb + srow * D_ + dq0 + 4 * q);   // batched loads
    }
    #pragma unroll
    for (int s = 0; s < 4; ++s) {
        v4f ev;
        ev.x = __builtin_amdgcn_exp2f(hv[s].x * K);
        ev.y = __builtin_amdgcn_exp2f(hv[s].y * K);
        ev.z = __builtin_amdgcn_exp2f(hv[s].z * K);
        ev.w = __builtin_amdgcn_exp2f(hv[s].w * K);
        *(v4f*)&buf[slot[s] * ST + scol[s]] = ev;
    }

    // batch the 8 uniform w-quads (one SMEM latency)
    float4 wqa[8];
    #pragma unroll
    for (int q = 0; q < 8; ++q)
        wqa[q] = *(const float4*)(w + dq0 + 4 * q);

    __builtin_amdgcn_wave_barrier();         // pin ds_writes before reads (own wave only)

    v4f acc[2][2];
    #pragma unroll
    for (int ii = 0; ii < 2; ++ii)
        #pragma unroll
        for (int jj = 0; jj < 2; ++jj) acc[ii][jj] = (v4f){0.f, 0.f, 0.f, 0.f};

    #pragma unroll
    for (int q = 0; q < 8; ++q) {            // 4-d block per step
        v4f wvv; wvv.x = wqa[q].x; wvv.y = wqa[q].y; wvv.z = wqa[q].z; wvv.w = wqa[q].w;
        v4f Ei[2], Ej[2];
        #pragma unroll
        for (int ii = 0; ii < 2; ++ii)       // slots ii*8+ig: all 32 banks once
            Ei[ii] = *(const v4f*)&buf[(ii * 8 + ig) * ST + 4 * q];
        #pragma unroll
        for (int jj = 0; jj < 2; ++jj)
            Ej[jj] = *(const v4f*)&buf[(16 + jj * 8 + jg) * ST + 4 * q];
        #pragma unroll
        for (int ii = 0; ii < 2; ++ii)
            #pragma unroll
            for (int jj = 0; jj < 2; ++jj) {
                v4f den = Ei[ii] * Ej[jj] + 1.0f;
                v4f rr;
                rr.x = __builtin_amdgcn_rcpf(den.x);
                rr.y = __builtin_amdgcn_rcpf(den.y);
                rr.z = __builtin_amdgcn_rcpf(den.z);
                rr.w = __builtin_amdgcn_rcpf(den.w);
                acc[ii][jj] += wvv * rr;
            }
    }

    // ---- partials to LDS ----
    #pragma unroll
    for (int ii = 0; ii < 2; ++ii)
        #pragma unroll
        for (int jj = 0; jj < 2; ++jj) {
            v4f a = acc[ii][jj];
            pr[wv][ig + 8 * ii][jg + 8 * jj] = a.x + a.y + a.z + a.w;
        }
    __syncthreads();

    // ---- combine 8 slices; threads 0..255 own one tile element each ----
    float val = 0.0f;
    const int row = (tid >> 4) & 15, col = tid & 15;
    if (tid < 256) {
        #pragma unroll
        for (int k = 0; k < 8; ++k) val += pr[k][row][col];
        val *= -2.0f;                        // shifted score
        sOut[((size_t)b * L_ + i0 + row) * L_ + j0 + col] = val;   // upper, coalesced
    }
    if (ti != tj) {                          // mirror via LDS transpose (block-uniform)
        if (tid < 256) sc[row][col] = val;
        __syncthreads();
        if (tid < 256)
            sOut[((size_t)b * L_ + j0 + row) * L_ + i0 + col] = sc[col][row];
    }
}

// Phase 2 (R17): 256 blocks x 512 thr (8 waves); 8 rows/block.
// A: softmax, wave w owns row w (alpha -> global + sc LDS).
// B: r-phase, wave w owns j in [64w,64w+64), racc[8] over the block's 8 rows;
//    H[b] read once per block -> 128MB L2 total (was 256MB).
// C: sc is dead -> union'd pr[8][8][256]; cross-wave reduce, coalesced store.
union SMem {
    float sc[8][L_];          // 16 KB (phases A,B)
    float pr[8][8][D_];       // 64 KB (phase C)
};

__global__ __launch_bounds__(512) void softmax_r_kernel(
    const float* __restrict__ H, float* __restrict__ rOut, float* __restrict__ aOut)
{
    __shared__ __align__(16) SMem u;

    const int tid  = threadIdx.x;
    const int blk  = blockIdx.x;     // 0..255
    const int b    = blk >> 6;
    const int i0   = (blk & 63) * 8;
    const int wv   = tid >> 6;       // wave 0..7
    const int lane = tid & 63;
    const float* Hb = H + (size_t)b * L_ * D_;
    const float L2E = 1.4426950408889634f;

    // ---- A: softmax, wave wv handles row wv ----
    {
        const int row = wv;
        float* aRow = aOut + ((size_t)b * L_ + i0 + row) * L_;
        float v[8];
        float m = -1e30f;
        #pragma unroll
        for (int k = 0; k < 8; ++k) {
            v[k] = aRow[lane + 64 * k];      // coalesced score reads (L2/L3-hot)
            m = fmaxf(m, v[k]);
        }
        #pragma unroll
        for (int off = 1; off < 64; off <<= 1)
            m = fmaxf(m, __shfl_xor(m, off, 64));
        float s = 0.0f;
        #pragma unroll
        for (int k = 0; k < 8; ++k) {
            v[k] = __builtin_amdgcn_exp2f((v[k] - m) * L2E);
            s += v[k];
        }
        #pragma unroll
        for (int off = 1; off < 64; off <<= 1)
            s += __shfl_xor(s, off, 64);
        const float inv = __builtin_amdgcn_rcpf(s);
        #pragma unroll
        for (int k = 0; k < 8; ++k) {
            float a = v[k] * inv;
            u.sc[row][lane + 64 * k] = a;
            aRow[lane + 64 * k] = a;         // overwrite scores with alpha in place
        }
    }
    __syncthreads();

    // ---- B: r-phase, wave-cooperative over j (64 j per wave), 8 rows ----
    const int jbase = 64 * wv;
    v4f racc[8];
    #pragma unroll
    for (int r = 0; r < 8; ++r) racc[r] = (v4f){0.f, 0.f, 0.f, 0.f};
    const v4f* Hb4 = (const v4f*)Hb;         // [512][64]

    #pragma unroll 2
    for (int js = 0; js < 64; js += 4) {
        v4f h[4];
        #pragma unroll
        for (int q = 0; q < 4; ++q)
            h[q] = Hb4[(size_t)(jbase + js + q) * (D_ / 4) + lane];
        #pragma unroll
        for (int r = 0; r < 8; ++r) {
            v4f av = *(const v4f*)&u.sc[r][jbase + js];   // b128 uniform broadcast
            #pragma unroll
            for (int q = 0; q < 4; ++q)
                racc[r] += av[q] * h[q];
        }
    }
    __syncthreads();                 // all sc reads done before pr overwrites it

    #pragma unroll
    for (int r = 0; r < 8; ++r)
        *(v4f*)&u.pr[wv][r][4 * lane] = racc[r];
    __syncthreads();

    // ---- C: reduce 8 wave-partials, write r (all 512 threads) ----
    {
        const int fq  = tid & 63;        // float4 index in D
        const int row = tid >> 6;        // 0..7
        v4f s = *(const v4f*)&u.pr[0][row][4 * fq];
        #pragma unroll
        for (int k = 1; k < 8; ++k)
            s += *(const v4f*)&u.pr[k][row][4 * fq];
        *(v4f*)&rOut[((size_t)b * L_ + i0 + row) * D_ + 4 * fq] = s;
    }
}

extern "C" void kernel_launch(void* const* d_in, const int* in_sizes, int n_in,
                              void* d_out, int out_size, void* d_ws, size_t ws_size,
                              hipStream_t stream) {
    const float* H = (const float*)d_in[0];
    const float* w = (const float*)d_in[1];
    // d_in[2] (bias) unused: softmax shift-invariance cancels it.
    float* rOut = (float*)d_out;
    float* aOut = rOut + (size_t)B_ * L_ * D_;   // alpha region doubles as score scratch

    score_kernel<<<dim3(B_ * NTRI16), 512, 0, stream>>>(H, w, aOut);
    softmax_r_kernel<<<dim3(B_ * (L_ / 8)), 512, 0, stream>>>(H, rOut, aOut);
}